// Round 5
// baseline (1299.346 us; speedup 1.0000x reference)
//
#include <hip/hip_runtime.h>
#include <cstdint>
#include <cstddef>

#define IMG 512
#define JD 192
#define SST 65   // stride for 64x64 LDS matrices (scalar access, conflict-free)

// ---------------------------------------------------------------------------
// K1: partial Gram. grid (4 chunks, 3 row-slabs of 64, 16 batches), 256 thr.
// 4x12 acc tile per lane, all-float4 LDS reads (balanced LDS/VALU).
// ---------------------------------------------------------------------------
__global__ __launch_bounds__(256) void k_gram(const float* __restrict__ x,
                                              float* __restrict__ part) {
  const int ck = blockIdx.x;
  const int sl = blockIdx.y;
  const int b  = blockIdx.z;
  const int t  = threadIdx.x;
  __shared__ float tile[32*JD];
  const int ty = t >> 4;          // 16 groups x 4 rows (slab of 64)
  const int tx = t & 15;          // 16 groups x 12 cols (192)
  const int r0 = sl*64 + ty*4;
  const int c0 = tx*12;
  float acc[4][12];
#pragma unroll
  for (int i=0;i<4;i++)
#pragma unroll
    for (int j=0;j<12;j++) acc[i][j]=0.f;
  const float* xb = x + (size_t)b*3*IMG*IMG;
  const int nbeg = ck*1024;
  for (int n0 = nbeg; n0 < nbeg+1024; n0 += 32) {
    for (int f = t; f < 32*JD; f += 256) {
      const int nl = f / JD, j = f - nl*JD;
      const int n = n0 + nl;
      const int hh = n >> 6, ww = n & 63;
      const int c = j >> 6, p = (j >> 3) & 7, q = j & 7;
      tile[nl*JD + j] = xb[(c*IMG + hh*8+p)*IMG + ww*8 + q];
    }
    __syncthreads();
#pragma unroll 4
    for (int nl = 0; nl < 32; nl++) {
      const float4 av = *(const float4*)(tile + nl*JD + r0);
      const float4 b0 = *(const float4*)(tile + nl*JD + c0);
      const float4 b1 = *(const float4*)(tile + nl*JD + c0 + 4);
      const float4 b2 = *(const float4*)(tile + nl*JD + c0 + 8);
      const float a4[4] = {av.x, av.y, av.z, av.w};
      const float b12[12] = {b0.x,b0.y,b0.z,b0.w,b1.x,b1.y,b1.z,b1.w,
                             b2.x,b2.y,b2.z,b2.w};
#pragma unroll
      for (int i=0;i<4;i++)
#pragma unroll
        for (int j=0;j<12;j++) acc[i][j] += a4[i]*b12[j];
    }
    __syncthreads();
  }
  float* dst = part + (((size_t)(b*3 + sl))*4 + ck) * (size_t)(64*JD);
#pragma unroll
  for (int i=0;i<4;i++)
#pragma unroll
    for (int j=0;j<12;j++)
      dst[(ty*4+i)*JD + c0+j] = acc[i][j];
}

// ---------------------------------------------------------------------------
// K2: reduce 4 chunk-partials -> Gs = G / 4096
// ---------------------------------------------------------------------------
__global__ __launch_bounds__(256) void k_greduce(const float* __restrict__ part,
                                                 float* __restrict__ Gs) {
  const int idx = blockIdx.x*256 + threadIdx.x;
  const int b = idx / (JD*JD);
  const int e = idx - b*(JD*JD);
  const int r = e / JD;
  const int sl = r >> 6;
  const int w = (r & 63)*JD + (e - r*JD);
  const float* p = part + ((size_t)(b*3+sl))*4*(64*JD) + w;
  float s = 0.f;
#pragma unroll
  for (int ck=0; ck<4; ck++) s += p[(size_t)ck*64*JD];
  Gs[idx] = s * (1.0f/4096.0f);
}

// ---------------------------------------------------------------------------
// K3: D = S*S for symmetric S (per batch), lower-tri tile pairs.
// ---------------------------------------------------------------------------
__global__ __launch_bounds__(256) void k_sq(const float* __restrict__ S,
                                            float* __restrict__ D) {
  const int tp = blockIdx.x;
  const int b  = blockIdx.y;
  int ti, tj;
  if      (tp==0){ti=0;tj=0;} else if (tp==1){ti=1;tj=0;}
  else if (tp==2){ti=1;tj=1;} else if (tp==3){ti=2;tj=0;}
  else if (tp==4){ti=2;tj=1;} else            {ti=2;tj=2;}
  const float* Sb = S + (size_t)b*JD*JD;
  float* Db = D + (size_t)b*JD*JD;
  __shared__ float Ar[64][33];
  __shared__ float Br[64][33];
  const int t = threadIdx.x;
  const int ty = t >> 4, tx = t & 15;
  float acc[4][4];
#pragma unroll
  for (int i=0;i<4;i++)
#pragma unroll
    for (int j=0;j<4;j++) acc[i][j]=0.f;
  for (int k0=0; k0<JD; k0+=32) {
    for (int f=t; f<2048; f+=256) {
      const int row = f >> 5, kk = f & 31;
      Ar[row][kk] = Sb[(ti*64+row)*JD + k0+kk];
      Br[row][kk] = Sb[(tj*64+row)*JD + k0+kk];
    }
    __syncthreads();
#pragma unroll 4
    for (int k=0;k<32;k++) {
      float va[4], vb[4];
#pragma unroll
      for (int i=0;i<4;i++) va[i] = Ar[ty*4+i][k];
#pragma unroll
      for (int j=0;j<4;j++) vb[j] = Br[tx*4+j][k];
#pragma unroll
      for (int i=0;i<4;i++)
#pragma unroll
        for (int j=0;j<4;j++) acc[i][j] += va[i]*vb[j];
    }
    __syncthreads();
  }
#pragma unroll
  for (int i=0;i<4;i++)
#pragma unroll
    for (int j=0;j<4;j++) {
      const int r = ti*64+ty*4+i, c = tj*64+tx*4+j;
      Db[r*JD+c] = acc[i][j];
      if (ti != tj) Db[c*JD+r] = acc[i][j];
    }
}

// ---------------------------------------------------------------------------
// K4 helpers (per-batch block, 256 threads)
// ---------------------------------------------------------------------------
__device__ inline void dev_stage_slab(const float* __restrict__ src, float* sl,
                                      int base, int t) {
  for (int f = t; f < 2048; f += 256) sl[f] = src[(base + (f>>6))*64 + (f&63)];
}

// Wout(192x64) = G(192x192) * Win(192x64); float4 b-operand reads.
__device__ void dev_matmul(const float* __restrict__ G, const float* __restrict__ Win,
                           float* __restrict__ Wout, float* sla, int t) {
  const int rg = t >> 2, cg = t & 3;
  float acc[3][16];
#pragma unroll
  for (int i=0;i<3;i++)
#pragma unroll
    for (int j=0;j<16;j++) acc[i][j]=0.f;
  for (int k0=0; k0<JD; k0+=32) {
    dev_stage_slab(Win, sla, k0, t);
    __syncthreads();
#pragma unroll 4
    for (int k=0;k<32;k++) {
      const float a0 = G[(rg*3+0)*JD + k0+k];
      const float a1 = G[(rg*3+1)*JD + k0+k];
      const float a2 = G[(rg*3+2)*JD + k0+k];
      const float* bp = sla + k*64 + cg*16;
      const float4 b0 = *(const float4*)(bp+0);
      const float4 b1 = *(const float4*)(bp+4);
      const float4 b2 = *(const float4*)(bp+8);
      const float4 b3 = *(const float4*)(bp+12);
      const float bb[16] = {b0.x,b0.y,b0.z,b0.w,b1.x,b1.y,b1.z,b1.w,
                            b2.x,b2.y,b2.z,b2.w,b3.x,b3.y,b3.z,b3.w};
#pragma unroll
      for (int j=0;j<16;j++) {
        acc[0][j] += a0*bb[j]; acc[1][j] += a1*bb[j]; acc[2][j] += a2*bb[j];
      }
    }
    __syncthreads();
  }
#pragma unroll
  for (int i=0;i<3;i++)
#pragma unroll
    for (int j=0;j<16;j++)
      Wout[(rg*3+i)*64 + cg*16 + j] = acc[i][j];
  __syncthreads();
}

// In-place ridge-CholQR of W (192x64). S1 is 64xSST LDS scratch.
__device__ void dev_orth(float* __restrict__ W, float* S1, float* sla,
                         float* rdv, float* misc, int t, float ridge) {
  const int ty = t >> 4, tx = t & 15;
  float acc[4][4];
#pragma unroll
  for (int i=0;i<4;i++)
#pragma unroll
    for (int j=0;j<4;j++) acc[i][j]=0.f;
  for (int r0=0; r0<JD; r0+=32) {
    dev_stage_slab(W, sla, r0, t);
    __syncthreads();
#pragma unroll 4
    for (int rl=0;rl<32;rl++) {
      const float4 va4 = *(const float4*)(sla + rl*64 + ty*4);
      const float4 vb4 = *(const float4*)(sla + rl*64 + tx*4);
      const float a4[4] = {va4.x, va4.y, va4.z, va4.w};
      const float b4[4] = {vb4.x, vb4.y, vb4.z, vb4.w};
#pragma unroll
      for (int i=0;i<4;i++)
#pragma unroll
        for (int j=0;j<4;j++) acc[i][j] += a4[i]*b4[j];
    }
    __syncthreads();
  }
#pragma unroll
  for (int i=0;i<4;i++)
#pragma unroll
    for (int j=0;j<4;j++)
      S1[(ty*4+i)*SST + tx*4+j] = acc[i][j];
  __syncthreads();
  if (t == 0) {
    float m = 0.f;
    for (int j=0;j<64;j++) m = fmaxf(m, S1[j*SST+j]);
    misc[0] = m * ridge;
  }
  __syncthreads();
  if (t < 64) S1[t*SST+t] += misc[0];
  for (int j=0;j<63;j++) {
    __syncthreads();
    const float invd = 1.0f / S1[j*SST+j];
    const int wd = 63 - j;
    for (int f=t; f<wd*64; f+=256) {
      const int i = j+1 + (f>>6);
      const int k = f & 63;
      if (k > j && k <= i)
        S1[i*SST+k] -= S1[i*SST+j]*S1[k*SST+j]*invd;
    }
  }
  __syncthreads();
  if (t < 64) rdv[t] = rsqrtf(S1[t*SST+t]);
  __syncthreads();
  for (int f=t; f<64*64; f+=256) {
    const int i = f>>6, k = f&63;
    if (k < i) S1[i*SST+k] *= rdv[k];
  }
  __syncthreads();
  if (t < JD) {
    float w[64];
#pragma unroll
    for (int c=0;c<64;c++) w[c] = W[t*64+c];
#pragma unroll
    for (int c=0;c<64;c++) {
      float v = w[c];
#pragma unroll
      for (int k=0;k<c;k++) v -= w[k]*S1[c*SST+k];
      w[c] = v * rdv[c];
    }
#pragma unroll
    for (int c=0;c<64;c++) W[t*64+c] = w[c];
  }
  __syncthreads();
}

// S1(64x64, stride SST) = X^T * Y  (both 192x64 global)
__device__ void dev_hgemm(const float* __restrict__ X, const float* __restrict__ Y,
                          float* S1, float* sla, float* slb, int t) {
  const int ty = t >> 4, tx = t & 15;
  float acc[4][4];
#pragma unroll
  for (int i=0;i<4;i++)
#pragma unroll
    for (int j=0;j<4;j++) acc[i][j]=0.f;
  for (int r0=0; r0<JD; r0+=32) {
    dev_stage_slab(X, sla, r0, t);
    dev_stage_slab(Y, slb, r0, t);
    __syncthreads();
#pragma unroll 4
    for (int rl=0;rl<32;rl++) {
      const float4 va4 = *(const float4*)(sla + rl*64 + ty*4);
      const float4 vb4 = *(const float4*)(slb + rl*64 + tx*4);
      const float a4[4] = {va4.x, va4.y, va4.z, va4.w};
      const float b4[4] = {vb4.x, vb4.y, vb4.z, vb4.w};
#pragma unroll
      for (int i=0;i<4;i++)
#pragma unroll
        for (int j=0;j<4;j++) acc[i][j] += a4[i]*b4[j];
    }
    __syncthreads();
  }
#pragma unroll
  for (int i=0;i<4;i++)
#pragma unroll
    for (int j=0;j<4;j++)
      S1[(ty*4+i)*SST + tx*4+j] = acc[i][j];
  __syncthreads();
}

// Householder tridiag of A (64x64, stride SST) in place; reflector tails kept
// in rows of A. Outputs: a[64] diag, b2[63] off^2, bsg[63] signed off,
// v0s/bts[62] reflector head/beta.
__device__ void dev_tridiag(float* __restrict__ A, float* a, float* b2,
                            float* bsg, float* v0s, float* bts,
                            float* vvec, float* wvec, int t) {
  for (int j=0; j<=61; j++) {
    const int m = 63 - j;
    if (t < 64) {
      float xi = (t < m) ? A[j*SST + (j+1+t)] : 0.f;
      float nr = xi*xi;
#pragma unroll
      for (int o=1;o<64;o<<=1) nr += __shfl_xor(nr, o);
      const float sig = sqrtf(nr);
      const float alpha = __shfl(xi, 0);
      const float sgn = (alpha >= 0.f) ? 1.f : -1.f;
      const float v0 = alpha + sgn*sig;
      const float beta = (sig > 1e-20f) ? 1.0f/(sig*fabsf(v0)) : 0.f;
      if (t < m) vvec[t] = (t==0) ? v0 : xi;
      if (t == 0) {
        a[j] = A[j*SST+j]; b2[j] = nr; bsg[j] = -sgn*sig;
        v0s[j] = v0; bts[j] = beta;
      }
      float pv = 0.f;
      if (t < m) {
        const float* row = A + (j+1+t)*SST + (j+1);
        for (int c=0;c<m;c++) pv += row[c]*vvec[c];
        pv *= beta;
      }
      float dp = (t<m) ? vvec[t]*pv : 0.f;
#pragma unroll
      for (int o=1;o<64;o<<=1) dp += __shfl_xor(dp, o);
      const float gamma = 0.5f*beta*dp;
      if (t < m) wvec[t] = pv - gamma*vvec[t];
    }
    __syncthreads();
    const int mm = m*m;
    for (int f=t; f<mm; f+=256) {
      const int r = f/m, c = f - r*m;
      A[(j+1+r)*SST + (j+1+c)] -= vvec[r]*wvec[c] + wvec[r]*vvec[c];
    }
    __syncthreads();
  }
  if (t == 0) {
    a[62] = A[62*SST+62];
    a[63] = A[63*SST+63];
    const float bb = A[62*SST+63];
    b2[62] = bb*bb;
    bsg[62] = bb;
  }
  __syncthreads();
}

__device__ inline int sturm_cnt(const float* a, const float* b2, float sig) {
  float d = a[0] - sig;
  int n = (d < 0.f) ? 1 : 0;
#pragma unroll 8
  for (int i=1;i<64;i++) {
    const float dd = (fabsf(d) < 1e-20f) ? -1e-20f : d;
    d = (a[i]-sig) - b2[i-1]/dd;
    n += (d < 0.f) ? 1 : 0;
  }
  return n;
}

__device__ inline float dguard(float d) {
  if (fabsf(d) < 1e-12f) return (d < 0.f) ? -1e-12f : 1e-12f;
  return d;
}

// ---------------------------------------------------------------------------
// K4: per-batch eigen stage. grid 16, 256 threads.
// R3-proven chain: cur=G16 cols; 3x{G16*W, ridge-orth}; clean orth ->
// H=W^T Gs W -> tridiag -> bisection -> twisted inv-iter -> CholQR32 ->
// backtransform -> M=(WV)(WV)^T
// ---------------------------------------------------------------------------
__global__ __launch_bounds__(256) void k_eig(const float* __restrict__ G16,
                                             const float* __restrict__ Gs,
                                             float* __restrict__ WaG,
                                             float* __restrict__ WbG,
                                             float* __restrict__ Mg) {
  const int b = blockIdx.x;
  const int t = threadIdx.x;
  __shared__ float SH[64*SST];     // orth Gram -> H -> reflector storage
  __shared__ float sla[2048];
  __shared__ float slb[2048];
  __shared__ float Vt[64*36];      // T-eigvecs -> backtransformed V (64x32)
  __shared__ float dpA[64*33];     // d+ table; later CholQR32 Gram
  __shared__ float dmA[64*33];     // d- table
  __shared__ float Bt[32*196];     // B^T staging (32 x 192)
  __shared__ float ps[8*33];
  __shared__ float rdv[64];
  __shared__ float a64[64];
  __shared__ float b2v[64];
  __shared__ float bsg[64];
  __shared__ float v0s[64];
  __shared__ float bts[64];
  __shared__ float vvec[64];
  __shared__ float wvec[64];
  __shared__ float lam[32];
  __shared__ float misc[8];

  const float* G16b = G16 + (size_t)b*JD*JD;
  const float* Gsb  = Gs  + (size_t)b*JD*JD;
  float* cur = WaG + (size_t)b*JD*64;
  float* oth = WbG + (size_t)b*JD*64;
  float* Mb  = Mg  + (size_t)b*JD*JD;

  // ---- stage 1: W = top-64 basis via G16 subspace iteration (3 mm, 4 orth) ----
  for (int f=t; f<JD*64; f+=256)
    cur[f] = G16b[(f>>6)*JD + (f&63)];
  __syncthreads();
  for (int it=0; it<3; it++) {
    dev_matmul(G16b, cur, oth, sla, t);
    dev_orth(oth, SH, sla, rdv, misc, t, 1e-6f);
    float* tmp = cur; cur = oth; oth = tmp;
  }
  dev_orth(cur, SH, sla, rdv, misc, t, 0.f);   // clean CholQR pass

  // ---- H = W^T Gs W  -> SH (stride SST) ----
  dev_matmul(Gsb, cur, oth, sla, t);           // T = Gs*W -> oth
  dev_hgemm(cur, oth, SH, sla, slb, t);        // H = W^T T

  // ---- tridiagonalize H in place ----
  dev_tridiag(SH, a64, b2v, bsg, v0s, bts, vvec, wvec, t);

  // ---- spectrum bounds (Gershgorin) ----
  if (t < 64) {
    const float bl = (t>0)  ? sqrtf(b2v[t-1]) : 0.f;
    const float br = (t<63) ? sqrtf(b2v[t])   : 0.f;
    float lo = a64[t] - bl - br, hi = a64[t] + bl + br;
#pragma unroll
    for (int o=1;o<64;o<<=1) {
      lo = fminf(lo, __shfl_xor(lo,o));
      hi = fmaxf(hi, __shfl_xor(hi,o));
    }
    if (t == 0) { misc[0] = lo - 1e-4f; misc[1] = hi + 1e-4f; }
  }
  __syncthreads();

  // ---- per-eigenvalue bisection: lane l -> ascending index 32+l ----
  if (t < 32) {
    const int r = 32 + t;
    float L = misc[0], H = misc[1];
    for (int it=0; it<30; it++) {
      const float mid = 0.5f*(L+H);
      const int cnt = sturm_cnt(a64, b2v, mid);
      if (cnt <= r) L = mid; else H = mid;
    }
    lam[t] = 0.5f*(L+H);
  }
  __syncthreads();

  // ---- twisted-factorization inverse iteration (lane l = one eigvec) ----
  if (t < 32) {
    const int l = t;
    const float lm = lam[l];
    float d = dguard(a64[0] - lm);
    dpA[0*33+l] = d;
    for (int i=1;i<64;i++) {
      d = dguard((a64[i]-lm) - b2v[i-1]/d);
      dpA[i*33+l] = d;
    }
    float e = dguard(a64[63] - lm);
    dmA[63*33+l] = e;
    for (int i=62;i>=0;i--) {
      e = dguard((a64[i]-lm) - b2v[i]/e);
      dmA[i*33+l] = e;
    }
    int ks = 0; float gbest = 1e30f;
    for (int i=0;i<64;i++) {
      const float g = fabsf(dpA[i*33+l] + dmA[i*33+l] - (a64[i]-lm));
      if (g < gbest) { gbest = g; ks = i; }
    }
    Vt[ks*36+l] = 1.f;
    float z = 1.f;
    for (int i=ks-1;i>=0;i--) {
      z = -(bsg[i]*z) / dpA[i*33+l];
      z = fminf(fmaxf(z, -1e18f), 1e18f);
      Vt[i*36+l] = z;
    }
    z = 1.f;
    for (int i=ks+1;i<64;i++) {
      z = -(bsg[i-1]*z) / dmA[i*33+l];
      z = fminf(fmaxf(z, -1e18f), 1e18f);
      Vt[i*36+l] = z;
    }
    float nr2 = 0.f;
    for (int i=0;i<64;i++) { const float zz = Vt[i*36+l]; nr2 += zz*zz; }
    const float inv = rsqrtf(nr2);
    for (int i=0;i<64;i++) Vt[i*36+l] *= inv;
  }
  __syncthreads();

  // ---- CholQR-32 safety pass on Vt ----
  for (int f=t; f<1024; f+=256) {
    const int i = f>>5, j = f&31;
    float s = 0.f;
    for (int r=0;r<64;r++) s += Vt[r*36+i]*Vt[r*36+j];
    dpA[i*33+j] = s;
  }
  __syncthreads();
  if (t == 0) {
    float m = 0.f;
    for (int j=0;j<32;j++) m = fmaxf(m, dpA[j*33+j]);
    misc[2] = m * 1e-7f;
  }
  __syncthreads();
  if (t < 32) dpA[t*33+t] += misc[2];
  for (int j=0;j<31;j++) {
    __syncthreads();
    const float invd = 1.0f / dpA[j*33+j];
    for (int f=t; f<(31-j)*32; f+=256) {
      const int i = j+1 + (f>>5);
      const int k = f & 31;
      if (k > j && k <= i)
        dpA[i*33+k] -= dpA[i*33+j]*dpA[k*33+j]*invd;
    }
  }
  __syncthreads();
  if (t < 32) rdv[t] = rsqrtf(dpA[t*33+t]);
  __syncthreads();
  for (int f=t; f<1024; f+=256) {
    const int i = f>>5, k = f&31;
    if (k < i) dpA[i*33+k] *= rdv[k];
  }
  __syncthreads();
  if (t < 64) {
    float w[32];
#pragma unroll
    for (int c=0;c<32;c++) w[c] = Vt[t*36+c];
#pragma unroll
    for (int c=0;c<32;c++) {
      float v = w[c];
#pragma unroll
      for (int k=0;k<c;k++) v -= w[k]*dpA[c*33+k];
      w[c] = v * rdv[c];
    }
#pragma unroll
    for (int c=0;c<32;c++) Vt[t*36+c] = w[c];
  }
  __syncthreads();

  // ---- backtransform: V = H_0 H_1 ... H_61 Vt  (2 barriers/reflector) ----
  for (int j=61; j>=0; j--) {
    const int m = 63 - j;
    const int c = t & 31, g = t >> 5;
    float s = 0.f;
    for (int r=g; r<m; r+=8) {
      const float vr = (r==0) ? v0s[j] : SH[j*SST + (j+1+r)];
      s += vr * Vt[(j+1+r)*36 + c];
    }
    ps[g*33+c] = s;
    __syncthreads();
    float wv = 0.f;
#pragma unroll
    for (int gg=0;gg<8;gg++) wv += ps[gg*33+c];
    wv *= bts[j];
    for (int r=g; r<m; r+=8) {
      const float vr = (r==0) ? v0s[j] : SH[j*SST + (j+1+r)];
      Vt[(j+1+r)*36 + c] -= vr * wv;
    }
    __syncthreads();
  }

  // ---- B^T = (W * V)^T  -> Bt (32 x 192, stride 196) ----
  if (t < JD) {
    float accv[32];
#pragma unroll
    for (int c=0;c<32;c++) accv[c] = 0.f;
    const float4* crow = (const float4*)(cur + t*64);
#pragma unroll 2
    for (int kb=0; kb<16; kb++) {
      const float4 av = crow[kb];
      const float a4[4] = {av.x, av.y, av.z, av.w};
#pragma unroll
      for (int ki=0; ki<4; ki++) {
        const float aa = a4[ki];
        const float* vrow = Vt + (kb*4+ki)*36;
        const float4 v0 = *(const float4*)(vrow+0);
        const float4 v1 = *(const float4*)(vrow+4);
        const float4 v2 = *(const float4*)(vrow+8);
        const float4 v3 = *(const float4*)(vrow+12);
        const float4 v4 = *(const float4*)(vrow+16);
        const float4 v5 = *(const float4*)(vrow+20);
        const float4 v6 = *(const float4*)(vrow+24);
        const float4 v7 = *(const float4*)(vrow+28);
        accv[0]+=aa*v0.x; accv[1]+=aa*v0.y; accv[2]+=aa*v0.z; accv[3]+=aa*v0.w;
        accv[4]+=aa*v1.x; accv[5]+=aa*v1.y; accv[6]+=aa*v1.z; accv[7]+=aa*v1.w;
        accv[8]+=aa*v2.x; accv[9]+=aa*v2.y; accv[10]+=aa*v2.z; accv[11]+=aa*v2.w;
        accv[12]+=aa*v3.x; accv[13]+=aa*v3.y; accv[14]+=aa*v3.z; accv[15]+=aa*v3.w;
        accv[16]+=aa*v4.x; accv[17]+=aa*v4.y; accv[18]+=aa*v4.z; accv[19]+=aa*v4.w;
        accv[20]+=aa*v5.x; accv[21]+=aa*v5.y; accv[22]+=aa*v5.z; accv[23]+=aa*v5.w;
        accv[24]+=aa*v6.x; accv[25]+=aa*v6.y; accv[26]+=aa*v6.z; accv[27]+=aa*v6.w;
        accv[28]+=aa*v7.x; accv[29]+=aa*v7.y; accv[30]+=aa*v7.z; accv[31]+=aa*v7.w;
      }
    }
#pragma unroll
    for (int c=0;c<32;c++) Bt[c*196 + t] = accv[c];
  }
  __syncthreads();

  // ---- M = B B^T (192x192) -> global ----
  for (int tt=t; tt<576; tt+=256) {
    const int tr = tt/24, tc = tt - tr*24;
    const int r0 = tr*8, c0 = tc*8;
    float acc2[8][8];
#pragma unroll
    for (int i=0;i<8;i++)
#pragma unroll
      for (int j=0;j<8;j++) acc2[i][j]=0.f;
    for (int k=0;k<32;k++) {
      const float* br = Bt + k*196;
      const float4 a0 = *(const float4*)(br + r0);
      const float4 a1 = *(const float4*)(br + r0 + 4);
      const float4 b0 = *(const float4*)(br + c0);
      const float4 b1 = *(const float4*)(br + c0 + 4);
      const float va[8] = {a0.x,a0.y,a0.z,a0.w,a1.x,a1.y,a1.z,a1.w};
      const float vb[8] = {b0.x,b0.y,b0.z,b0.w,b1.x,b1.y,b1.z,b1.w};
#pragma unroll
      for (int i=0;i<8;i++)
#pragma unroll
        for (int j=0;j<8;j++) acc2[i][j] += va[i]*vb[j];
    }
#pragma unroll
    for (int i=0;i<8;i++)
#pragma unroll
      for (int j=0;j<8;j++)
        Mb[(r0+i)*JD + c0+j] = acc2[i][j];
  }
}

// ---------------------------------------------------------------------------
// K5: recon = A*M fused depatchify. grid (64 patch-blocks of 64, 16 batches).
// 4x12 acc tile, all-float4 LDS reads (balanced LDS/VALU).
// ---------------------------------------------------------------------------
__global__ __launch_bounds__(256) void k_recon(const float* __restrict__ x,
                                               const float* __restrict__ Mg,
                                               float* __restrict__ out) {
  const int nb = blockIdx.x;
  const int b  = blockIdx.y;
  const int t  = threadIdx.x;
  __shared__ float Atv[16*68];     // [jj][patch] transposed A-tile
  __shared__ float Mt[16*JD];
  const float* xb = x + (size_t)b*3*IMG*IMG;
  const float* Mb = Mg + (size_t)b*JD*JD;
  float* ob = out + (size_t)b*3*IMG*IMG;
  const int pg = t >> 4;   // 16 groups x 4 patches (64 per block)
  const int jg = t & 15;   // 16 groups x 12 out-cols
  float acc[4][12];
#pragma unroll
  for (int i=0;i<4;i++)
#pragma unroll
    for (int j=0;j<12;j++) acc[i][j]=0.f;
  for (int j0=0; j0<JD; j0+=16) {
    for (int f=t; f<1024; f+=256) {
      const int jj = f >> 6, nl = f & 63;
      const int j = j0 + jj;
      const int n = nb*64 + nl;
      const int hh = n >> 6, ww = n & 63;
      const int c = j >> 6, p = (j >> 3) & 7, q = j & 7;
      Atv[jj*68 + nl] = xb[(c*IMG + hh*8+p)*IMG + ww*8 + q];
    }
    for (int f=t; f<3072; f+=256) {
      const int jj = f / JD, cc = f - jj*JD;
      Mt[jj*JD + cc] = Mb[(j0+jj)*JD + cc];
    }
    __syncthreads();
#pragma unroll 4
    for (int jj=0;jj<16;jj++) {
      const float4 av = *(const float4*)(Atv + jj*68 + pg*4);
      const float4 m0 = *(const float4*)(Mt + jj*JD + jg*12);
      const float4 m1 = *(const float4*)(Mt + jj*JD + jg*12 + 4);
      const float4 m2 = *(const float4*)(Mt + jj*JD + jg*12 + 8);
      const float a4[4] = {av.x, av.y, av.z, av.w};
      const float mm[12] = {m0.x,m0.y,m0.z,m0.w,m1.x,m1.y,m1.z,m1.w,
                            m2.x,m2.y,m2.z,m2.w};
#pragma unroll
      for (int i=0;i<4;i++)
#pragma unroll
        for (int j=0;j<12;j++) acc[i][j] += a4[i]*mm[j];
    }
    __syncthreads();
  }
#pragma unroll
  for (int i=0;i<4;i++) {
    const int n = nb*64 + pg*4 + i;
    const int hh = n >> 6, ww = n & 63;
#pragma unroll
    for (int j4=0;j4<3;j4++) {
      const int jo = jg*12 + j4*4;
      const int c = jo >> 6, p = (jo >> 3) & 7, q = jo & 7;
      const float4 v = make_float4(acc[i][j4*4+0], acc[i][j4*4+1],
                                   acc[i][j4*4+2], acc[i][j4*4+3]);
      *(float4*)(ob + (size_t)(c*IMG + hh*8+p)*IMG + ww*8 + q) = v;
    }
  }
}

// ---------------------------------------------------------------------------
extern "C" void kernel_launch(void* const* d_in, const int* in_sizes, int n_in,
                              void* d_out, int out_size, void* d_ws, size_t ws_size,
                              hipStream_t stream) {
  (void)in_sizes; (void)n_in; (void)out_size; (void)ws_size;
  const float* x = (const float*)d_in[0];
  float* out = (float*)d_out;
  float* ws  = (float*)d_ws;

  float* part = ws;             // 16*3*4*64*192 = 2,359,296 floats
  float* Gs   = ws + 2359296;
  float* P0   = ws + 2949120;
  float* P1   = ws + 3538944;
  float* Mg   = ws;             // overlay (part dead after k_greduce)
  float* Wa   = ws + 589824;
  float* Wb   = ws + 786432;

  k_gram  <<<dim3(4,3,16), 256, 0, stream>>>(x, part);
  k_greduce<<<2304,        256, 0, stream>>>(part, Gs);
  k_sq    <<<dim3(6,16),   256, 0, stream>>>(Gs, P0);   // Gs^2
  k_sq    <<<dim3(6,16),   256, 0, stream>>>(P0, P1);   // Gs^4
  k_sq    <<<dim3(6,16),   256, 0, stream>>>(P1, P0);   // Gs^8
  k_sq    <<<dim3(6,16),   256, 0, stream>>>(P0, P1);   // Gs^16
  k_eig   <<<16,           256, 0, stream>>>(P1, Gs, Wa, Wb, Mg);
  k_recon <<<dim3(64,16),  256, 0, stream>>>(x, Mg, out);
}